// Round 7
// baseline (148.629 us; speedup 1.0000x reference)
//
#include <hip/hip_runtime.h>

// Problem constants (B=1 fixed by reference)
#define HW_TOTAL (480 * 640)           // 307200 pixels
#define NC 12                           // output channels (C-1)
#define VOX_TOTAL_C (240 * 144 * 240)   // 8,294,400 voxels (divisible by 32)

#define REC_STRIDE 16                   // floats per voxel record (64 B line)

typedef float f32x4 __attribute__((ext_vector_type(4)));

// ---------------------------------------------------------------------------
// k1 (after 1 MB bitmap memset): scatter pixel records.
// x reads are pixel-indexed -> coalesced across lanes. rec[v] gets all 12
// channels + 16B pad as four float4 stores = one full 64-B line -> no
// write-allocate RMW. bitmap bit via atomicOr (map values unique -> no rec
// conflicts; atomicOr commutative -> deterministic).
__global__ void scatter_rec_kernel(const float* __restrict__ x,
                                   const int* __restrict__ map,
                                   float* __restrict__ rec,
                                   unsigned int* __restrict__ bitmap) {
    int p = blockIdx.x * blockDim.x + threadIdx.x;
    if (p >= HW_TOTAL) return;
    int v = map[p];
    if (v <= 0) return;                 // invalid pixel (dropped)
    float vals[NC];
#pragma unroll
    for (int c = 0; c < NC; ++c)
        vals[c] = x[(size_t)(c + 1) * HW_TOTAL + p];
    f32x4* dst = (f32x4*)(rec + (size_t)v * REC_STRIDE);
    f32x4 a = {vals[0], vals[1], vals[2],  vals[3]};
    f32x4 b = {vals[4], vals[5], vals[6],  vals[7]};
    f32x4 c4 = {vals[8], vals[9], vals[10], vals[11]};
    f32x4 z = {0.f, 0.f, 0.f, 0.f};
    dst[0] = a; dst[1] = b; dst[2] = c4; dst[3] = z;   // full 64-B line
    atomicOr(&bitmap[v >> 5], 1u << (v & 31));
}

// ---------------------------------------------------------------------------
// k2: streaming gather. 4 voxels/thread. Loads gated on bitmap nibble
// (~13% of threads take them; FETCH at line granularity = ~18 MB). Stores
// are a SINGLE unconditional path covering full 64-B lines per instruction.
// R7 A/B: regular (write-back) stores instead of nontemporal — fill kernels
// prove regular full-line streams hit 6.7+ TB/s; R6's NT stream ran ~4.9.
__global__ void gather_rec_kernel(const float* __restrict__ rec,
                                  const unsigned int* __restrict__ bitmap,
                                  float* __restrict__ out) {
    int t = blockIdx.x * blockDim.x + threadIdx.x;   // 4-voxel group
    if (t >= VOX_TOTAL_C / 4) return;
    unsigned int word = bitmap[t >> 3];              // 8 lanes share a word
    unsigned int nib = (word >> ((t & 7) * 4)) & 0xFu;
    size_t base = (size_t)t * 4;

    f32x4 A[4][3];
    const f32x4 z = {0.f, 0.f, 0.f, 0.f};
#pragma unroll
    for (int k = 0; k < 4; ++k) {
        A[k][0] = z; A[k][1] = z; A[k][2] = z;
    }
    if (nib) {                                       // rare: gated loads only
#pragma unroll
        for (int k = 0; k < 4; ++k) {
            if (nib & (1u << k)) {
                const f32x4* r = (const f32x4*)(rec + (base + (size_t)k) * REC_STRIDE);
                A[k][0] = r[0]; A[k][1] = r[1]; A[k][2] = r[2];
            }
        }
    }
    // Single unconditional store path — full-line regular stores.
#pragma unroll
    for (int c = 0; c < NC; ++c) {
        f32x4 o = { A[0][c >> 2][c & 3], A[1][c >> 2][c & 3],
                    A[2][c >> 2][c & 3], A[3][c >> 2][c & 3] };
        *(f32x4*)(out + (size_t)c * VOX_TOTAL_C + base) = o;
    }
}

// ---------------------------------------------------------------------------
// Fallback (only if ws_size were too small): memset + naive scatter (R1 path).
__global__ void naive_scatter_kernel(const float* __restrict__ x,
                                     const int* __restrict__ map,
                                     float* __restrict__ out) {
    int p = blockIdx.x * blockDim.x + threadIdx.x;
    if (p >= HW_TOTAL) return;
    int v = map[p];
    if (v <= 0) return;
#pragma unroll
    for (int c = 0; c < NC; ++c)
        out[(size_t)c * VOX_TOTAL_C + (size_t)v] = x[(size_t)(c + 1) * HW_TOTAL + p];
}

extern "C" void kernel_launch(void* const* d_in, const int* in_sizes, int n_in,
                              void* d_out, int out_size, void* d_ws, size_t ws_size,
                              hipStream_t stream) {
    const float* x = (const float*)d_in[0];      // (1, 13, 480, 640) f32
    const int* map = (const int*)d_in[1];        // (1, 307200) i32
    float* out = (float*)d_out;                  // (1, 12, 240, 144, 240) f32

    const size_t rec_bytes = (size_t)VOX_TOTAL_C * REC_STRIDE * sizeof(float); // 531 MB
    const size_t bitmap_bytes = VOX_TOTAL_C / 8;                               // 1.04 MB

    if (ws_size < rec_bytes + bitmap_bytes) {
        // Safety net (ws is ~1.59 GB in this harness; shouldn't trigger).
        hipMemsetAsync(out, 0, (size_t)NC * VOX_TOTAL_C * sizeof(float), stream);
        naive_scatter_kernel<<<HW_TOTAL / 256, 256, 0, stream>>>(x, map, out);
        return;
    }

    float* rec = (float*)d_ws;
    unsigned int* bitmap = (unsigned int*)((char*)d_ws + rec_bytes);

    // Zero only the bitmap (1 MB) every call; rec is gated by bitmap bits.
    hipMemsetAsync(bitmap, 0, bitmap_bytes, stream);

    scatter_rec_kernel<<<HW_TOTAL / 256, 256, 0, stream>>>(x, map, rec, bitmap);

    const int total = VOX_TOTAL_C / 4;               // 2,073,600 threads
    gather_rec_kernel<<<(total + 255) / 256, 256, 0, stream>>>(rec, bitmap, out);
}

// Round 8
// 147.223 us; speedup vs baseline: 1.0095x; 1.0095x over previous
//
#include <hip/hip_runtime.h>

// Problem constants (B=1 fixed by reference)
#define HW_TOTAL (480 * 640)           // 307200 pixels
#define NC 12                           // output channels (C-1)
#define VOX_TOTAL_C (240 * 144 * 240)   // 8,294,400 voxels (divisible by 32)

#define REC_STRIDE 16                   // floats per voxel record (64 B line)
#define NGROUPS (VOX_TOTAL_C / 4)       // 2,073,600 4-voxel groups
#define GSTRIDE (NGROUPS / 4)           // 518,400 threads, 4 groups each

typedef float f32x4 __attribute__((ext_vector_type(4)));

// ---------------------------------------------------------------------------
// k1 (after 1 MB bitmap memset): scatter pixel records.
// x reads are pixel-indexed -> coalesced across lanes. rec[v] gets all 12
// channels + 16B pad as four NT float4 stores = one full 64-B line (no RMW,
// no L2 pollution). bitmap bit via atomicOr (map values unique -> no rec
// conflicts; atomicOr commutative -> deterministic).
__global__ void scatter_rec_kernel(const float* __restrict__ x,
                                   const int* __restrict__ map,
                                   float* __restrict__ rec,
                                   unsigned int* __restrict__ bitmap) {
    int p = blockIdx.x * blockDim.x + threadIdx.x;
    if (p >= HW_TOTAL) return;
    int v = map[p];
    if (v <= 0) return;                 // invalid pixel (dropped)
    float vals[NC];
#pragma unroll
    for (int c = 0; c < NC; ++c)
        vals[c] = x[(size_t)(c + 1) * HW_TOTAL + p];
    f32x4* dst = (f32x4*)(rec + (size_t)v * REC_STRIDE);
    f32x4 a = {vals[0], vals[1], vals[2],  vals[3]};
    f32x4 b = {vals[4], vals[5], vals[6],  vals[7]};
    f32x4 c4 = {vals[8], vals[9], vals[10], vals[11]};
    f32x4 z = {0.f, 0.f, 0.f, 0.f};
    __builtin_nontemporal_store(a,  dst + 0);
    __builtin_nontemporal_store(b,  dst + 1);
    __builtin_nontemporal_store(c4, dst + 2);
    __builtin_nontemporal_store(z,  dst + 3);          // full 64-B line
    atomicOr(&bitmap[v >> 5], 1u << (v & 31));
}

// ---------------------------------------------------------------------------
// k2: streaming gather, grid-stride x4 (fill-kernel shape). Each thread
// handles groups {t, t+G, t+2G, t+3G}; every store instruction is a fully
// contiguous 1024-B wave-write, and the 4 unrolled iterations give the
// scheduler independent load->store chains to overlap (R6 had exactly one
// chain per thread). Loads gated on bitmap nibble (~13% of threads). Single
// unconditional NT store path (R5 lesson: divergent dual-path stores ->
// partial-line NT writes, +21% WRITE_SIZE). NT keeps L2 clean for rec loads
// (R7 lesson: regular stores -> dirty L2 -> load stalls, 148 us).
__global__ void gather_rec_kernel(const float* __restrict__ rec,
                                  const unsigned int* __restrict__ bitmap,
                                  float* __restrict__ out) {
    const int t = blockIdx.x * blockDim.x + threadIdx.x;   // [0, GSTRIDE)
    if (t >= GSTRIDE) return;
#pragma unroll
    for (int i = 0; i < 4; ++i) {
        const int g = t + i * GSTRIDE;                 // 4-voxel group index
        unsigned int word = bitmap[g >> 3];            // 8 groups share a word
        unsigned int nib = (word >> ((g & 7) * 4)) & 0xFu;
        size_t base = (size_t)g * 4;

        f32x4 A[4][3];
        const f32x4 z = {0.f, 0.f, 0.f, 0.f};
#pragma unroll
        for (int k = 0; k < 4; ++k) {
            A[k][0] = z; A[k][1] = z; A[k][2] = z;
        }
        if (nib) {                                     // rare: gated loads
#pragma unroll
            for (int k = 0; k < 4; ++k) {
                if (nib & (1u << k)) {
                    const f32x4* r = (const f32x4*)(rec + (base + (size_t)k) * REC_STRIDE);
                    A[k][0] = r[0]; A[k][1] = r[1]; A[k][2] = r[2];
                }
            }
        }
#pragma unroll
        for (int c = 0; c < NC; ++c) {
            f32x4 o = { A[0][c >> 2][c & 3], A[1][c >> 2][c & 3],
                        A[2][c >> 2][c & 3], A[3][c >> 2][c & 3] };
            __builtin_nontemporal_store(o, (f32x4*)(out + (size_t)c * VOX_TOTAL_C + base));
        }
    }
}

// ---------------------------------------------------------------------------
// Fallback (only if ws_size were too small): memset + naive scatter (R1 path).
__global__ void naive_scatter_kernel(const float* __restrict__ x,
                                     const int* __restrict__ map,
                                     float* __restrict__ out) {
    int p = blockIdx.x * blockDim.x + threadIdx.x;
    if (p >= HW_TOTAL) return;
    int v = map[p];
    if (v <= 0) return;
#pragma unroll
    for (int c = 0; c < NC; ++c)
        out[(size_t)c * VOX_TOTAL_C + (size_t)v] = x[(size_t)(c + 1) * HW_TOTAL + p];
}

extern "C" void kernel_launch(void* const* d_in, const int* in_sizes, int n_in,
                              void* d_out, int out_size, void* d_ws, size_t ws_size,
                              hipStream_t stream) {
    const float* x = (const float*)d_in[0];      // (1, 13, 480, 640) f32
    const int* map = (const int*)d_in[1];        // (1, 307200) i32
    float* out = (float*)d_out;                  // (1, 12, 240, 144, 240) f32

    const size_t rec_bytes = (size_t)VOX_TOTAL_C * REC_STRIDE * sizeof(float); // 531 MB
    const size_t bitmap_bytes = VOX_TOTAL_C / 8;                               // 1.04 MB

    if (ws_size < rec_bytes + bitmap_bytes) {
        // Safety net (ws is ~1.59 GB in this harness; shouldn't trigger).
        hipMemsetAsync(out, 0, (size_t)NC * VOX_TOTAL_C * sizeof(float), stream);
        naive_scatter_kernel<<<HW_TOTAL / 256, 256, 0, stream>>>(x, map, out);
        return;
    }

    float* rec = (float*)d_ws;
    unsigned int* bitmap = (unsigned int*)((char*)d_ws + rec_bytes);

    // Zero only the bitmap (1 MB) every call; rec is gated by bitmap bits.
    hipMemsetAsync(bitmap, 0, bitmap_bytes, stream);

    scatter_rec_kernel<<<HW_TOTAL / 256, 256, 0, stream>>>(x, map, rec, bitmap);

    // gather: 518,400 threads x 4 groups = 2,073,600 groups
    gather_rec_kernel<<<(GSTRIDE + 255) / 256, 256, 0, stream>>>(rec, bitmap, out);
}

// Round 9
// 96.233 us; speedup vs baseline: 1.5445x; 1.5299x over previous
//
#include <hip/hip_runtime.h>

// Problem constants (B=1 fixed by reference)
#define HW_TOTAL (480 * 640)           // 307200 pixels
#define NC 12                           // output channels (C-1)
#define VOX_TOTAL_C (240 * 144 * 240)   // 8,294,400 voxels (divisible by 32)

#define REC_STRIDE 16                   // floats per voxel record (64 B line)
#define NGROUPS (VOX_TOTAL_C / 4)       // 2,073,600 4-voxel groups
#define GBLOCKS (NGROUPS / 256)         // 8100 group-blocks (exact)

typedef float f32x4 __attribute__((ext_vector_type(4)));

// ---------------------------------------------------------------------------
// k1 (after 1 MB bitmap memset): scatter pixel records. REGULAR stores (R8
// lesson: NT scatter stores are 64 scattered partial-line writes per instr;
// regular stores let L2 merge the 4 16-B stores into one full dirty line).
// x reads pixel-indexed -> coalesced. bitmap bit via atomicOr (map values
// unique -> no rec conflicts; atomicOr commutative -> deterministic).
__global__ void scatter_rec_kernel(const float* __restrict__ x,
                                   const int* __restrict__ map,
                                   float* __restrict__ rec,
                                   unsigned int* __restrict__ bitmap) {
    int p = blockIdx.x * blockDim.x + threadIdx.x;
    if (p >= HW_TOTAL) return;
    int v = map[p];
    if (v <= 0) return;                 // invalid pixel (dropped)
    float vals[NC];
#pragma unroll
    for (int c = 0; c < NC; ++c)
        vals[c] = x[(size_t)(c + 1) * HW_TOTAL + p];
    f32x4* dst = (f32x4*)(rec + (size_t)v * REC_STRIDE);
    f32x4 a = {vals[0], vals[1], vals[2],  vals[3]};
    f32x4 b = {vals[4], vals[5], vals[6],  vals[7]};
    f32x4 c4 = {vals[8], vals[9], vals[10], vals[11]};
    f32x4 z = {0.f, 0.f, 0.f, 0.f};
    dst[0] = a; dst[1] = b; dst[2] = c4; dst[3] = z;   // full 64-B line
    atomicOr(&bitmap[v >> 5], 1u << (v & 31));
}

// ---------------------------------------------------------------------------
// k2: streaming gather, channel-quad split. Block b: channel-quad cq = b%3
// (channels 4cq..4cq+3), group range (b/3)*256 .. +255. Each wave writes only
// 4 NT store streams (R6 had 12; R8's 48 regressed; fill's 1 hits 6.7 TB/s
// -> stream count per wave is the suspected limiter). Valid voxels load one
// 16-B f32x4 slice of their rec line; the 3 cq-blocks sharing a group range
// are dispatch-adjacent so the shared L3 serves the repeat line touches.
// Single unconditional NT store path (R5: divergent stores -> partial lines;
// R7: regular out stores -> 148 us).
__global__ void gather_rec_kernel(const float* __restrict__ rec,
                                  const unsigned int* __restrict__ bitmap,
                                  float* __restrict__ out) {
    const int b = blockIdx.x;
    const int cq = b % 3;                            // channel-quad 0..2
    const int g = (b / 3) * 256 + threadIdx.x;       // 4-voxel group (exact fit)
    unsigned int word = bitmap[g >> 3];              // 8 groups share a word
    unsigned int nib = (word >> ((g & 7) * 4)) & 0xFu;
    size_t base = (size_t)g * 4;

    f32x4 A[4];
    const f32x4 z = {0.f, 0.f, 0.f, 0.f};
    A[0] = z; A[1] = z; A[2] = z; A[3] = z;
    if (nib) {                                       // rare: gated loads only
#pragma unroll
        for (int k = 0; k < 4; ++k) {
            if (nib & (1u << k)) {
                A[k] = *(const f32x4*)(rec + (base + (size_t)k) * REC_STRIDE
                                           + (size_t)cq * 4);
            }
        }
    }
    const int c0 = cq * 4;
    // Single unconditional store path — 4 full-line NT streams per wave.
#pragma unroll
    for (int c = 0; c < 4; ++c) {
        f32x4 o = { A[0][c], A[1][c], A[2][c], A[3][c] };
        __builtin_nontemporal_store(o,
            (f32x4*)(out + (size_t)(c0 + c) * VOX_TOTAL_C + base));
    }
}

// ---------------------------------------------------------------------------
// Fallback (only if ws_size were too small): memset + naive scatter (R1 path).
__global__ void naive_scatter_kernel(const float* __restrict__ x,
                                     const int* __restrict__ map,
                                     float* __restrict__ out) {
    int p = blockIdx.x * blockDim.x + threadIdx.x;
    if (p >= HW_TOTAL) return;
    int v = map[p];
    if (v <= 0) return;
#pragma unroll
    for (int c = 0; c < NC; ++c)
        out[(size_t)c * VOX_TOTAL_C + (size_t)v] = x[(size_t)(c + 1) * HW_TOTAL + p];
}

extern "C" void kernel_launch(void* const* d_in, const int* in_sizes, int n_in,
                              void* d_out, int out_size, void* d_ws, size_t ws_size,
                              hipStream_t stream) {
    const float* x = (const float*)d_in[0];      // (1, 13, 480, 640) f32
    const int* map = (const int*)d_in[1];        // (1, 307200) i32
    float* out = (float*)d_out;                  // (1, 12, 240, 144, 240) f32

    const size_t rec_bytes = (size_t)VOX_TOTAL_C * REC_STRIDE * sizeof(float); // 531 MB
    const size_t bitmap_bytes = VOX_TOTAL_C / 8;                               // 1.04 MB

    if (ws_size < rec_bytes + bitmap_bytes) {
        // Safety net (ws is ~1.59 GB in this harness; shouldn't trigger).
        hipMemsetAsync(out, 0, (size_t)NC * VOX_TOTAL_C * sizeof(float), stream);
        naive_scatter_kernel<<<HW_TOTAL / 256, 256, 0, stream>>>(x, map, out);
        return;
    }

    float* rec = (float*)d_ws;
    unsigned int* bitmap = (unsigned int*)((char*)d_ws + rec_bytes);

    // Zero only the bitmap (1 MB) every call; rec is gated by bitmap bits.
    hipMemsetAsync(bitmap, 0, bitmap_bytes, stream);

    scatter_rec_kernel<<<HW_TOTAL / 256, 256, 0, stream>>>(x, map, rec, bitmap);

    // gather: 3 channel-quads x 8100 group-blocks = 24300 blocks
    gather_rec_kernel<<<GBLOCKS * 3, 256, 0, stream>>>(rec, bitmap, out);
}